// Round 6
// baseline (202.357 us; speedup 1.0000x reference)
//
#include <hip/hip_runtime.h>
#include <math.h>

// Problem constants (GeoFormer.generate_proposal, ScanNet config)
#define BB 4
#define QQ 128
#define NN 50000
#define CC 20
#define ROWS (BB * QQ)          // 512
#define NV4 (NN / 4)            // 12500 float4 per row
#define TPB 256
#define BPR 4                   // blocks per row
#define QUOTA (NV4 / BPR)       // 3125 f32x4 per block
#define FULL_ITERS 12           // 3125 = 12*256 + 53
#define TAIL 53
#define THRESH_CNT 50
#define MIN_CLS 4
#define GIDS_V4 ((BB * NN) / 4) // 50000 f32x4 of global_ids
#define GPB2 25                 // gid f32x4 per block in kB (2048 blocks)

// Fallback (single-kernel) constants
#define TPB1 1024
#define FULL1 12
#define TAIL1 212
#define GPB 98

typedef float f32x4 __attribute__((ext_vector_type(4)));
typedef int   i32x4 __attribute__((ext_vector_type(4)));
typedef unsigned long long u64;

// Tiny workspace: per-row per-block partials (no atomics, no bitmask).
struct WsSmall {
    float psum[ROWS][BPR];
    int   pcnt[ROWS][BPR];
    int   cls[ROWS];
};   // ~20.5 KB

// ===================== Phase-separated path =====================

// kA: PURE READ. Streams ml+sp, reduces sigmoid sum / count block-locally,
// writes only 2 scalars per block (+cls once per row). No bulk stores at
// all -> chip-wide pure-read traffic. Side effect: leaves ml fully
// L3-resident for kB (102 MB < 256 MB, back-to-back dispatches).
__global__ __launch_bounds__(256) void kA_reduce(
        const float* __restrict__ mask_logits,
        const int*   __restrict__ seg_pred,
        const float* __restrict__ cls_logits,
        WsSmall* __restrict__ ws) {
    const int row = blockIdx.y;
    const int b   = row >> 7;
    const int bx  = blockIdx.x;

    // Row-uniform argmax over C=20 (strict '>' forward scan = jnp.argmax).
    const float* cp = cls_logits + row * CC;
    float best = cp[0];
    int cls = 0;
    #pragma unroll
    for (int c = 1; c < CC; ++c) {
        float v = cp[c];
        if (v > best) { best = v; cls = c; }
    }

    const f32x4* __restrict__ ml =
        (const f32x4*)(mask_logits + (size_t)row * NN) + bx * QUOTA;
    const i32x4* __restrict__ sp =
        (const i32x4*)(seg_pred + b * NN) + bx * QUOTA;

    const int t = threadIdx.x;
    float lsum = 0.0f;
    int   lcnt = 0;

    #pragma unroll 4
    for (int i = 0; i < FULL_ITERS; ++i) {
        f32x4 vv = ml[i * TPB + t];
        i32x4 ss = sp[i * TPB + t];
        bool c0 = (vv.x > 0.0f) & (ss.x == cls);
        bool c1 = (vv.y > 0.0f) & (ss.y == cls);
        bool c2 = (vv.z > 0.0f) & (ss.z == cls);
        bool c3 = (vv.w > 0.0f) & (ss.w == cls);
        float g0 = 1.0f / (1.0f + __expf(-vv.x));
        float g1 = 1.0f / (1.0f + __expf(-vv.y));
        float g2 = 1.0f / (1.0f + __expf(-vv.z));
        float g3 = 1.0f / (1.0f + __expf(-vv.w));
        lsum += (c0 ? g0 : 0.0f) + (c1 ? g1 : 0.0f)
              + (c2 ? g2 : 0.0f) + (c3 ? g3 : 0.0f);
        lcnt += (int)c0 + (int)c1 + (int)c2 + (int)c3;
    }
    if (t < TAIL) {
        const int idx = FULL_ITERS * TPB + t;
        f32x4 vv = ml[idx];
        i32x4 ss = sp[idx];
        bool c0 = (vv.x > 0.0f) & (ss.x == cls);
        bool c1 = (vv.y > 0.0f) & (ss.y == cls);
        bool c2 = (vv.z > 0.0f) & (ss.z == cls);
        bool c3 = (vv.w > 0.0f) & (ss.w == cls);
        float g0 = 1.0f / (1.0f + __expf(-vv.x));
        float g1 = 1.0f / (1.0f + __expf(-vv.y));
        float g2 = 1.0f / (1.0f + __expf(-vv.z));
        float g3 = 1.0f / (1.0f + __expf(-vv.w));
        lsum += (c0 ? g0 : 0.0f) + (c1 ? g1 : 0.0f)
              + (c2 ? g2 : 0.0f) + (c3 ? g3 : 0.0f);
        lcnt += (int)c0 + (int)c1 + (int)c2 + (int)c3;
    }

    #pragma unroll
    for (int offr = 32; offr > 0; offr >>= 1) {
        lsum += __shfl_down(lsum, offr);
        lcnt += __shfl_down(lcnt, offr);
    }
    __shared__ float ssum[4];
    __shared__ int   scnt[4];
    const int wave = t >> 6;
    const int lane = t & 63;
    if (lane == 0) { ssum[wave] = lsum; scnt[wave] = lcnt; }
    __syncthreads();
    if (t == 0) {
        ws->psum[row][bx] = ssum[0] + ssum[1] + ssum[2] + ssum[3];
        ws->pcnt[row][bx] = scnt[0] + scnt[1] + scnt[2] + scnt[3];
        if (bx == 0) ws->cls[row] = cls;
    }
}

// kB: WRITE-DOMINATED. Re-reads ml (L3-hot from kA) + sp, recomputes the
// 1-bit selection (no sigmoid needed), NT-streams the float mask with
// valid already folded in. Finalize (scores/valid/cls) done per-row by
// the bx==0 block; gids slice folded in (25 f32x4/block x 2048 blocks).
__global__ __launch_bounds__(256) void kB_write(
        const float* __restrict__ mask_logits,
        const int*   __restrict__ seg_pred,
        const int*   __restrict__ fg,
        float* __restrict__ out,
        const WsSmall* __restrict__ ws) {
    const int row = blockIdx.y;
    const int b   = row >> 7;
    const int bx  = blockIdx.x;

    // Row-uniform finalize from partials (uniform addresses -> scalar loads).
    const int   cls = ws->cls[row];
    const float sum = ws->psum[row][0] + ws->psum[row][1]
                    + ws->psum[row][2] + ws->psum[row][3];
    const int   cnt = ws->pcnt[row][0] + ws->pcnt[row][1]
                    + ws->pcnt[row][2] + ws->pcnt[row][3];
    const bool  valid  = (cnt >= THRESH_CNT) && (cls >= MIN_CLS);
    const float validf = valid ? 1.0f : 0.0f;

    const int t = threadIdx.x;
    if (bx == 0 && t == 0) {
        float* tail = out + (size_t)ROWS * NN;
        tail[row]            = valid ? (sum / (float)max(cnt, 1)) : 0.0f;  // scores
        tail[ROWS + row]     = validf;                                     // valid
        tail[2 * ROWS + row] = (float)cls;                                 // cls_pred
    }

    const f32x4* __restrict__ ml =
        (const f32x4*)(mask_logits + (size_t)row * NN) + bx * QUOTA;
    const i32x4* __restrict__ sp =
        (const i32x4*)(seg_pred + b * NN) + bx * QUOTA;
    f32x4* __restrict__ om =
        (f32x4*)(out + (size_t)row * NN) + bx * QUOTA;

    #pragma unroll 4
    for (int i = 0; i < FULL_ITERS; ++i) {
        f32x4 vv = ml[i * TPB + t];
        i32x4 ss = sp[i * TPB + t];
        f32x4 o;
        o.x = ((vv.x > 0.0f) & (ss.x == cls)) ? validf : 0.0f;
        o.y = ((vv.y > 0.0f) & (ss.y == cls)) ? validf : 0.0f;
        o.z = ((vv.z > 0.0f) & (ss.z == cls)) ? validf : 0.0f;
        o.w = ((vv.w > 0.0f) & (ss.w == cls)) ? validf : 0.0f;
        __builtin_nontemporal_store(o, &om[i * TPB + t]);
    }
    if (t < TAIL) {
        const int idx = FULL_ITERS * TPB + t;
        f32x4 vv = ml[idx];
        i32x4 ss = sp[idx];
        f32x4 o;
        o.x = ((vv.x > 0.0f) & (ss.x == cls)) ? validf : 0.0f;
        o.y = ((vv.y > 0.0f) & (ss.y == cls)) ? validf : 0.0f;
        o.z = ((vv.z > 0.0f) & (ss.z == cls)) ? validf : 0.0f;
        o.w = ((vv.w > 0.0f) & (ss.w == cls)) ? validf : 0.0f;
        __builtin_nontemporal_store(o, &om[idx]);
    }

    // gids slice: block g = row*BPR+bx converts f32x4 [g*25, g*25+25).
    if (t < GPB2) {
        const int g = (row * BPR + bx) * GPB2 + t;
        if (g < GIDS_V4) {
            float* gids = out + (size_t)ROWS * NN + 3 * ROWS;
            i32x4 v = ((const i32x4*)fg)[g];
            f32x4 o;
            o.x = (float)v.x; o.y = (float)v.y; o.z = (float)v.z; o.w = (float)v.w;
            __builtin_nontemporal_store(o, &((f32x4*)gids)[g]);
        }
    }
}

// ===================== Fallback: R5 single-kernel =====================

__global__ __launch_bounds__(1024) void k1_fused(
        const float* __restrict__ mask_logits,
        const int*   __restrict__ seg_pred,
        const float* __restrict__ cls_logits,
        const int*   __restrict__ fg,
        float* __restrict__ out) {
    const int row = blockIdx.x;
    const int b   = row >> 7;

    const float* cp = cls_logits + row * CC;
    float best = cp[0];
    int cls = 0;
    #pragma unroll
    for (int c = 1; c < CC; ++c) {
        float v = cp[c];
        if (v > best) { best = v; cls = c; }
    }

    const f32x4* __restrict__ ml = (const f32x4*)(mask_logits + (size_t)row * NN);
    const i32x4* __restrict__ sp = (const i32x4*)(seg_pred + b * NN);
    f32x4* __restrict__ om = (f32x4*)(out + (size_t)row * NN);

    const int t = threadIdx.x;
    u64   bits = 0;
    float lsum = 0.0f;
    int   lcnt = 0;

    #pragma unroll 4
    for (int i = 0; i < FULL1; ++i) {
        f32x4 vv = ml[i * TPB1 + t];
        i32x4 ss = sp[i * TPB1 + t];
        bool c0 = (vv.x > 0.0f) & (ss.x == cls);
        bool c1 = (vv.y > 0.0f) & (ss.y == cls);
        bool c2 = (vv.z > 0.0f) & (ss.z == cls);
        bool c3 = (vv.w > 0.0f) & (ss.w == cls);
        float g0 = 1.0f / (1.0f + __expf(-vv.x));
        float g1 = 1.0f / (1.0f + __expf(-vv.y));
        float g2 = 1.0f / (1.0f + __expf(-vv.z));
        float g3 = 1.0f / (1.0f + __expf(-vv.w));
        lsum += (c0 ? g0 : 0.0f) + (c1 ? g1 : 0.0f)
              + (c2 ? g2 : 0.0f) + (c3 ? g3 : 0.0f);
        lcnt += (int)c0 + (int)c1 + (int)c2 + (int)c3;
        u64 nib = (u64)c0 | ((u64)c1 << 1) | ((u64)c2 << 2) | ((u64)c3 << 3);
        bits |= nib << (4 * i);
    }
    if (t < TAIL1) {
        const int idx = FULL1 * TPB1 + t;
        f32x4 vv = ml[idx];
        i32x4 ss = sp[idx];
        bool c0 = (vv.x > 0.0f) & (ss.x == cls);
        bool c1 = (vv.y > 0.0f) & (ss.y == cls);
        bool c2 = (vv.z > 0.0f) & (ss.z == cls);
        bool c3 = (vv.w > 0.0f) & (ss.w == cls);
        float g0 = 1.0f / (1.0f + __expf(-vv.x));
        float g1 = 1.0f / (1.0f + __expf(-vv.y));
        float g2 = 1.0f / (1.0f + __expf(-vv.z));
        float g3 = 1.0f / (1.0f + __expf(-vv.w));
        lsum += (c0 ? g0 : 0.0f) + (c1 ? g1 : 0.0f)
              + (c2 ? g2 : 0.0f) + (c3 ? g3 : 0.0f);
        lcnt += (int)c0 + (int)c1 + (int)c2 + (int)c3;
        u64 nib = (u64)c0 | ((u64)c1 << 1) | ((u64)c2 << 2) | ((u64)c3 << 3);
        bits |= nib << (4 * FULL1);
    }

    #pragma unroll
    for (int offr = 32; offr > 0; offr >>= 1) {
        lsum += __shfl_down(lsum, offr);
        lcnt += __shfl_down(lcnt, offr);
    }
    __shared__ float ssum[16];
    __shared__ int   scnt[16];
    const int wave = t >> 6;
    const int lane = t & 63;
    if (lane == 0) { ssum[wave] = lsum; scnt[wave] = lcnt; }
    __syncthreads();
    float sum = 0.0f;
    int   cnt = 0;
    #pragma unroll
    for (int w = 0; w < 16; ++w) { sum += ssum[w]; cnt += scnt[w]; }
    const bool  valid  = (cnt >= THRESH_CNT) && (cls >= MIN_CLS);
    const float validf = valid ? 1.0f : 0.0f;

    if (t == 0) {
        float* tail = out + (size_t)ROWS * NN;
        tail[row]            = valid ? (sum / (float)max(cnt, 1)) : 0.0f;
        tail[ROWS + row]     = validf;
        tail[2 * ROWS + row] = (float)cls;
    }

    #pragma unroll 4
    for (int i = 0; i < FULL1; ++i) {
        u64 nib = bits >> (4 * i);
        f32x4 o;
        o.x = (nib & 1ull) ? validf : 0.0f;
        o.y = (nib & 2ull) ? validf : 0.0f;
        o.z = (nib & 4ull) ? validf : 0.0f;
        o.w = (nib & 8ull) ? validf : 0.0f;
        __builtin_nontemporal_store(o, &om[i * TPB1 + t]);
    }
    if (t < TAIL1) {
        u64 nib = bits >> (4 * FULL1);
        f32x4 o;
        o.x = (nib & 1ull) ? validf : 0.0f;
        o.y = (nib & 2ull) ? validf : 0.0f;
        o.z = (nib & 4ull) ? validf : 0.0f;
        o.w = (nib & 8ull) ? validf : 0.0f;
        __builtin_nontemporal_store(o, &om[FULL1 * TPB1 + t]);
    }

    if (t < GPB) {
        const int g = row * GPB + t;
        if (g < GIDS_V4) {
            float* gids = out + (size_t)ROWS * NN + 3 * ROWS;
            i32x4 v = ((const i32x4*)fg)[g];
            f32x4 o;
            o.x = (float)v.x; o.y = (float)v.y; o.z = (float)v.z; o.w = (float)v.w;
            __builtin_nontemporal_store(o, &((f32x4*)gids)[g]);
        }
    }
}

// ===================== launch =====================

extern "C" void kernel_launch(void* const* d_in, const int* in_sizes, int n_in,
                              void* d_out, int out_size, void* d_ws, size_t ws_size,
                              hipStream_t stream) {
    const float* mask_logits = (const float*)d_in[0];   // [B,Q,N] f32
    const float* cls_logits  = (const float*)d_in[1];   // [B,Q,C] f32
    const int*   seg_pred    = (const int*)d_in[2];     // [B,N]   int32
    const int*   fg_idxs     = (const int*)d_in[3];     // [B*N]   int32

    float* out = (float*)d_out;

    // Output layout (flat, return order):
    //   [0, ROWS*NN)  proposal_masks | +ROWS scores | +ROWS valid
    //   +ROWS cls_pred | +BB*NN global_ids
    if (ws_size >= sizeof(WsSmall)) {
        // Phase-separated: pure-read reduce, then write-dominated pass
        // (ml re-read is L3-resident from kA; no bulk data round-trip).
        WsSmall* ws = (WsSmall*)d_ws;
        dim3 g(BPR, ROWS);
        kA_reduce<<<g, TPB, 0, stream>>>(mask_logits, seg_pred, cls_logits, ws);
        kB_write<<<g, TPB, 0, stream>>>(mask_logits, seg_pred, fg_idxs, out, ws);
    } else {
        k1_fused<<<ROWS, TPB1, 0, stream>>>(mask_logits, seg_pred, cls_logits,
                                            fg_idxs, out);
    }
}

// Round 7
// 190.109 us; speedup vs baseline: 1.0644x; 1.0644x over previous
//
#include <hip/hip_runtime.h>
#include <math.h>

// Problem constants (GeoFormer.generate_proposal, ScanNet config)
#define BB 4
#define QQ 128
#define NN 50000
#define CC 20
#define ROWS (BB * QQ)          // 512
#define NV4 (NN / 4)            // 12500 float4 per row
#define TPB1 1024               // one block per row, 16 waves
#define FULL1 12                // 12 * 1024 = 12288 f32x4
#define TAIL1 212               // 12500 - 12288
#define THRESH_CNT 50
#define MIN_CLS 4
#define GIDS_V4 ((BB * NN) / 4)     // 50000 f32x4 of global_ids
#define GPB 98                      // ceil(50000/512) gid f32x4 per block

typedef float f32x4 __attribute__((ext_vector_type(4)));
typedef int   i32x4 __attribute__((ext_vector_type(4)));
typedef unsigned long long u64;

// Single-dispatch kernel (best measured config, R5: 189.5 µs total).
// ONE block per row (512 x 1024). Phase A: stream-read ml+sp, pack
// per-point selection into a register u64 (13 nibbles), block-reduce
// sigmoid sum/count -> valid locally (no workspace, no atomics). Phase B:
// unpack bits, NT-stream the float mask (invalid rows written as zeros).
// Phase C: this block's 98-element slice of the global_ids copy.
//
// Ceiling model (R0-R6): kernel-window bus bytes = harness poison-fill L3
// drain (~256 MB) + our mandatory ~155 MB (53 MB ml fetch surviving in
// L3 + 102 MB mask write) at ~6.5 TB/s bus ceiling => ~63 µs floor.
// Six structural variants (grids 512-6656 blocks, occupancy 34-72%,
// NT/plain stores, sched fences, 1-4 dispatches, two phase-separation
// schemes) all land 64-68 µs. Structure-independent; bytes are minimal.
__global__ __launch_bounds__(1024) void k1_fused(
        const float* __restrict__ mask_logits,
        const int*   __restrict__ seg_pred,
        const float* __restrict__ cls_logits,
        const int*   __restrict__ fg,
        float* __restrict__ out) {
    const int row = blockIdx.x;          // 0..511  (b*Q + q)
    const int b   = row >> 7;            // row / Q

    // Row-uniform argmax over C=20 (blockIdx-uniform addresses -> s_loads).
    // jnp.argmax tie-break = first max -> strict '>' forward scan.
    const float* cp = cls_logits + row * CC;
    float best = cp[0];
    int cls = 0;
    #pragma unroll
    for (int c = 1; c < CC; ++c) {
        float v = cp[c];
        if (v > best) { best = v; cls = c; }
    }

    const f32x4* __restrict__ ml = (const f32x4*)(mask_logits + (size_t)row * NN);
    const i32x4* __restrict__ sp = (const i32x4*)(seg_pred + b * NN);
    f32x4* __restrict__ om = (f32x4*)(out + (size_t)row * NN);

    const int t = threadIdx.x;
    u64   bits = 0;                      // 13 nibbles of selection bits
    float lsum = 0.0f;
    int   lcnt = 0;

    // ---------------- Phase A: pure read + reduce ----------------
    #pragma unroll 4
    for (int i = 0; i < FULL1; ++i) {
        f32x4 vv = ml[i * TPB1 + t];
        i32x4 ss = sp[i * TPB1 + t];
        // sigmoid(x) > 0.5  <=>  x > 0 ; branchless
        bool c0 = (vv.x > 0.0f) & (ss.x == cls);
        bool c1 = (vv.y > 0.0f) & (ss.y == cls);
        bool c2 = (vv.z > 0.0f) & (ss.z == cls);
        bool c3 = (vv.w > 0.0f) & (ss.w == cls);
        float g0 = 1.0f / (1.0f + __expf(-vv.x));
        float g1 = 1.0f / (1.0f + __expf(-vv.y));
        float g2 = 1.0f / (1.0f + __expf(-vv.z));
        float g3 = 1.0f / (1.0f + __expf(-vv.w));
        lsum += (c0 ? g0 : 0.0f) + (c1 ? g1 : 0.0f)
              + (c2 ? g2 : 0.0f) + (c3 ? g3 : 0.0f);
        lcnt += (int)c0 + (int)c1 + (int)c2 + (int)c3;
        u64 nib = (u64)c0 | ((u64)c1 << 1) | ((u64)c2 << 2) | ((u64)c3 << 3);
        bits |= nib << (4 * i);
    }
    if (t < TAIL1) {
        const int idx = FULL1 * TPB1 + t;
        f32x4 vv = ml[idx];
        i32x4 ss = sp[idx];
        bool c0 = (vv.x > 0.0f) & (ss.x == cls);
        bool c1 = (vv.y > 0.0f) & (ss.y == cls);
        bool c2 = (vv.z > 0.0f) & (ss.z == cls);
        bool c3 = (vv.w > 0.0f) & (ss.w == cls);
        float g0 = 1.0f / (1.0f + __expf(-vv.x));
        float g1 = 1.0f / (1.0f + __expf(-vv.y));
        float g2 = 1.0f / (1.0f + __expf(-vv.z));
        float g3 = 1.0f / (1.0f + __expf(-vv.w));
        lsum += (c0 ? g0 : 0.0f) + (c1 ? g1 : 0.0f)
              + (c2 ? g2 : 0.0f) + (c3 ? g3 : 0.0f);
        lcnt += (int)c0 + (int)c1 + (int)c2 + (int)c3;
        u64 nib = (u64)c0 | ((u64)c1 << 1) | ((u64)c2 << 2) | ((u64)c3 << 3);
        bits |= nib << (4 * FULL1);      // bits 48..51
    }

    // ---------------- block-local reduce -> valid ----------------
    #pragma unroll
    for (int offr = 32; offr > 0; offr >>= 1) {
        lsum += __shfl_down(lsum, offr);
        lcnt += __shfl_down(lcnt, offr);
    }
    __shared__ float ssum[16];
    __shared__ int   scnt[16];
    const int wave = t >> 6;
    const int lane = t & 63;
    if (lane == 0) { ssum[wave] = lsum; scnt[wave] = lcnt; }
    __syncthreads();
    float sum = 0.0f;
    int   cnt = 0;
    #pragma unroll
    for (int w = 0; w < 16; ++w) { sum += ssum[w]; cnt += scnt[w]; }
    const bool  valid  = (cnt >= THRESH_CNT) && (cls >= MIN_CLS);
    const float validf = valid ? 1.0f : 0.0f;

    if (t == 0) {
        float* tail = out + (size_t)ROWS * NN;
        tail[row]            = valid ? (sum / (float)max(cnt, 1)) : 0.0f;  // scores
        tail[ROWS + row]     = validf;                                     // valid
        tail[2 * ROWS + row] = (float)cls;                                 // cls_pred
    }

    // ---------------- Phase B: pure NT write from registers ----------------
    #pragma unroll 4
    for (int i = 0; i < FULL1; ++i) {
        u64 nib = bits >> (4 * i);
        f32x4 o;
        o.x = (nib & 1ull) ? validf : 0.0f;
        o.y = (nib & 2ull) ? validf : 0.0f;
        o.z = (nib & 4ull) ? validf : 0.0f;
        o.w = (nib & 8ull) ? validf : 0.0f;
        __builtin_nontemporal_store(o, &om[i * TPB1 + t]);
    }
    if (t < TAIL1) {
        u64 nib = bits >> (4 * FULL1);
        f32x4 o;
        o.x = (nib & 1ull) ? validf : 0.0f;
        o.y = (nib & 2ull) ? validf : 0.0f;
        o.z = (nib & 4ull) ? validf : 0.0f;
        o.w = (nib & 8ull) ? validf : 0.0f;
        __builtin_nontemporal_store(o, &om[FULL1 * TPB1 + t]);
    }

    // ---------------- Phase C: this block's global_ids slice ----------------
    if (t < GPB) {
        const int g = row * GPB + t;
        if (g < GIDS_V4) {
            float* gids = out + (size_t)ROWS * NN + 3 * ROWS;
            i32x4 v = ((const i32x4*)fg)[g];
            f32x4 o;
            o.x = (float)v.x; o.y = (float)v.y; o.z = (float)v.z; o.w = (float)v.w;
            __builtin_nontemporal_store(o, &((f32x4*)gids)[g]);
        }
    }
}

extern "C" void kernel_launch(void* const* d_in, const int* in_sizes, int n_in,
                              void* d_out, int out_size, void* d_ws, size_t ws_size,
                              hipStream_t stream) {
    const float* mask_logits = (const float*)d_in[0];   // [B,Q,N] f32
    const float* cls_logits  = (const float*)d_in[1];   // [B,Q,C] f32
    const int*   seg_pred    = (const int*)d_in[2];     // [B,N]   int32
    const int*   fg_idxs     = (const int*)d_in[3];     // [B*N]   int32

    float* out = (float*)d_out;
    (void)d_ws; (void)ws_size;          // workspace unused

    // Output layout (flat, return order):
    //   [0, ROWS*NN)  proposal_masks | +ROWS scores | +ROWS valid
    //   +ROWS cls_pred | +BB*NN global_ids
    k1_fused<<<ROWS, TPB1, 0, stream>>>(mask_logits, seg_pred, cls_logits,
                                        fg_idxs, out);
}